// Round 2
// baseline (235.629 us; speedup 1.0000x reference)
//
#include <hip/hip_runtime.h>

#define BB 32
#define LL 1024
#define HH 384
#define H4 (HH / 4)    // 96 float4 per row
#define TT 128         // t-positions per gather block
#define NT 256         // threads per block

// ---- kernel A: per-batch inclusive cumsum of durations -> d_ws ----
__global__ __launch_bounds__(NT) void scan_kernel(
    const int* __restrict__ dur,   // (B, L)
    int* __restrict__ cum)         // (B, L) in workspace
{
    __shared__ int psum[NT];
    const int tid = threadIdx.x;
    const int b   = blockIdx.x;

    int4 d = ((const int4*)(dur + (size_t)b * LL))[tid];
    const int p0 = d.x;
    const int p1 = p0 + d.y;
    const int p2 = p1 + d.z;
    const int p3 = p2 + d.w;
    psum[tid] = p3;
    __syncthreads();
    #pragma unroll
    for (int off = 1; off < NT; off <<= 1) {
        const int v = (tid >= off) ? psum[tid - off] : 0;
        __syncthreads();
        psum[tid] += v;
        __syncthreads();
    }
    const int excl = (tid > 0) ? psum[tid - 1] : 0;
    int4 o;
    o.x = excl + p0;
    o.y = excl + p1;
    o.z = excl + p2;
    o.w = excl + p3;
    ((int4*)(cum + (size_t)b * LL))[tid] = o;
}

// ---- kernel B: binary-search + gather + mask ----
__global__ __launch_bounds__(NT) void gather_kernel(
    const float* __restrict__ ehs,   // (B, L, H)
    const int* __restrict__ cum,     // (B, L) from workspace
    float* __restrict__ out,         // (B, T, H)
    float* __restrict__ mask,        // (B, T)
    int T)
{
    __shared__ int scum[LL];
    __shared__ int sidx[TT];

    const int tid = threadIdx.x;
    const int b   = blockIdx.y;
    const int t0  = blockIdx.x * TT;

    // stage cum row into LDS (4 KB, one int4 per thread)
    ((int4*)scum)[tid] = ((const int4*)(cum + (size_t)b * LL))[tid];
    __syncthreads();

    const int total = scum[LL - 1];

    // idx[t] = #(cum <= t), clamped to L-1  (searchsorted side='right')
    if (tid < TT) {
        const int t = t0 + tid;
        int lo = 0, hi = LL;
        while (lo < hi) {
            const int mid = (lo + hi) >> 1;
            if (scum[mid] <= t) lo = mid + 1; else hi = mid;
        }
        sidx[tid] = (lo < LL - 1) ? lo : (LL - 1);
        if (t < T) mask[(size_t)b * T + t] = (t < total) ? 1.0f : 0.0f;
    }
    __syncthreads();

    // gather: TT t's x 96 float4, coalesced read and write
    const float4* __restrict__ src_base = (const float4*)(ehs + (size_t)b * LL * HH);
    float4* __restrict__ out4 = (float4*)out;
    const float4 zero4 = make_float4(0.f, 0.f, 0.f, 0.f);

    for (int w = tid; w < TT * H4; w += NT) {
        const int tl = w / H4;          // magic-mul division
        const int v  = w - tl * H4;
        const int t  = t0 + tl;
        if (t >= T) break;              // t non-decreasing in w per thread
        float4 val = zero4;
        if (t < total) {
            val = src_base[(size_t)sidx[tl] * H4 + v];
        }
        out4[((size_t)b * T + t) * H4 + v] = val;
    }
}

extern "C" void kernel_launch(void* const* d_in, const int* in_sizes, int n_in,
                              void* d_out, int out_size, void* d_ws, size_t ws_size,
                              hipStream_t stream) {
    const float* ehs = (const float*)d_in[0];
    const int*   dur = (const int*)d_in[1];

    const int T = out_size / (BB * (HH + 1));   // out_size = B*T*(H+1)

    float* out  = (float*)d_out;
    float* mask = (float*)d_out + (size_t)BB * T * HH;
    int*   cum  = (int*)d_ws;                   // B*L ints = 128 KB

    scan_kernel<<<dim3(BB), dim3(NT), 0, stream>>>(dur, cum);

    dim3 grid((T + TT - 1) / TT, BB);
    gather_kernel<<<grid, dim3(NT), 0, stream>>>(ehs, cum, out, mask, T);
}